// Round 12
// baseline (429.856 us; speedup 1.0000x reference)
//
#include <hip/hip_runtime.h>

// GraphAttentionLayer v14: B=16, M=2048, F_IN=128, F_OUT=64, ALPHA=0.2
// out = elu( softmax_j( mask(adj, leaky_relu(f1_i + f2_j)) ) @ (h@W) )
// Algebra: h' = ((P @ h) @ W)/den, f1 = h@(W@a1), f2 = h@(W@a2).
//
// v14. Decomposition (total = kernels + ~262us harness): v13 kernels ~155
// = prep 10 + pack 45 + main ~100. v12-vs-v13 showed stage-reg dbuf was
// neutral -> main's 3750 cy/tile is lockstep latency at 2 waves/SIMD
// (grid 512 = 2 blocks/CU; rows/wave=16 is MFMA-fixed).
//  - k_pp: prep+pack MERGED (independent inputs) -> prep hides under the
//    adj stream. ~47us.
//  - k_main: token-split x2 -> 1024 blocks x 32 rows; wave (rg,wh) = 16
//    rows x 32-tile half. 12 waves/CU (3/SIMD, +50%); 32 steps (2 tiles
//    in flight/step, 32KB ping-pong lbuf) -> half the barriers.
//  - masks in VGPRs (8 words/thread) + shfl with LITERAL step index
//    (fully unrolled -> static reg indexing); frees 17KB LDS -> 3 blk/CU.
// Numerics: score bits + per-half den order + epilogue unchanged;
// half-merge reorder is the v8-verified pattern. absmax 0.001953125.

#define M_     2048
#define FIN_   128
#define F_     64
#define ALPHA_ 0.2f
#define HS_    132     // prep LDS h-tile stride (floats)
#define WT_    132     // Tsum row stride (floats)

typedef float  float4_ __attribute__((ext_vector_type(4)));
typedef short  short8  __attribute__((ext_vector_type(8)));
typedef int    int4_   __attribute__((ext_vector_type(4)));
typedef unsigned int u32x4 __attribute__((ext_vector_type(4)));
typedef unsigned short u16;
typedef unsigned int   u32;

// packed f32x2 -> bf16x2 (RNE)
static __device__ __forceinline__ u32 cvtpk(float lo, float hi) {
    u32 r;
    asm("v_cvt_pk_bf16_f32 %0, %1, %2" : "=v"(r) : "v"(lo), "v"(hi));
    return r;
}

// non-temporal 16B load (read-once stream; don't pollute caches)
static __device__ __forceinline__ int4_ ntload4(const int* p) {
    return __builtin_nontemporal_load((const int4_*)p);
}

// ---------------------------------------------------------------------------
// Phase 1 (merged): blocks 0..1023 = prep (hbf B-frags + f1/f2);
//                   blocks 1024..3071 = pack (adj -> 1-bit masks, coalesced).
// hbf fragment layout: ((b*64 + t)*8 + nt)*64 + l (16B per entry);
// lane l holds B[n = nt*16 + (l&15)][k = (l>>4)*8 .. +7], token-pair packed.
// mask word w: tokens [w*32, w*32+32), bit j = adj[w*32+j] > 0.
// ---------------------------------------------------------------------------
__global__ __launch_bounds__(256, 4) void k_pp(
    const float* __restrict__ h, const int* __restrict__ adj,
    const float* __restrict__ W, const float* __restrict__ a,
    u16* __restrict__ hbf, float* __restrict__ f1all,
    float* __restrict__ f2all, u32* __restrict__ mask)
{
    __shared__ float a_s[2 * F_];
    __shared__ float wa1[FIN_], wa2[FIN_];
    __shared__ float hs[32 * HS_];

    const int tid = threadIdx.x;

    if (blockIdx.x >= 1024) {
        // ---------------- pack: coalesced streaming ----------------
        const int l = tid & 63;
        u32 s = (blockIdx.x - 1024) * 4 + (tid >> 6);   // wave id 0..8191
#pragma unroll 4
        for (int it = 0; it < 32; ++it, s += 8192) {
            int4_ v = ntload4(adj + (size_t)s * 256 + l * 4);
            u32 m = ((v[0] > 0 ? 1u : 0u) | (v[1] > 0 ? 2u : 0u)
                   | (v[2] > 0 ? 4u : 0u) | (v[3] > 0 ? 8u : 0u)) << ((l & 7) * 4);
            m |= __shfl_xor(m, 1, 64);
            m |= __shfl_xor(m, 2, 64);
            m |= __shfl_xor(m, 4, 64);
            if ((l & 7) == 0) mask[s * 8 + (l >> 3)] = m;
        }
        return;
    }

    // ---------------- prep ----------------
    const u32 bid = blockIdx.x;
    const u32 lg  = (bid & 7) * 128 + (bid >> 3);   // XCD x: batches 2x,2x+1
    const int b   = lg >> 6;
    const int t   = lg & 63;

    if (tid < 128) a_s[tid] = a[tid];

    const int tok = tid >> 3, f0 = (tid & 7) * 16;
    const float* hp = h + ((size_t)(b * M_ + t * 32 + tok)) * FIN_ + f0;
    float4_ x0 = *(const float4_*)hp;
    float4_ x1 = *(const float4_*)(hp + 4);
    float4_ x2 = *(const float4_*)(hp + 8);
    float4_ x3 = *(const float4_*)(hp + 12);
    __syncthreads();   // a_s ready

    if (tid < FIN_) {
        float s1 = 0.f, s2 = 0.f;
#pragma unroll 8
        for (int n = 0; n < F_; ++n) {
            float wv = W[tid * F_ + n];
            s1 += wv * a_s[n];
            s2 += wv * a_s[F_ + n];
        }
        wa1[tid] = s1;
        wa2[tid] = s2;
    }

    float* hr = hs + tok * HS_ + f0;
    *(float4_*)(hr)      = x0;
    *(float4_*)(hr + 4)  = x1;
    *(float4_*)(hr + 8)  = x2;
    *(float4_*)(hr + 12) = x3;
    __syncthreads();   // hs + wa ready

    {
        const int l = tid & 63, lc = l & 15, q = l >> 4;
        const int nt0 = (tid >> 6) * 2;
        u32x4* ob = (u32x4*)hbf + ((size_t)(b * 64 + t)) * 8 * 64;
#pragma unroll
        for (int ni = 0; ni < 2; ++ni) {
            const int nt = nt0 + ni;
            const float* cp = hs + (q * 8) * HS_ + nt * 16 + lc;
            u32x4 wv;
            wv[0] = cvtpk(cp[0 * HS_], cp[1 * HS_]);
            wv[1] = cvtpk(cp[2 * HS_], cp[3 * HS_]);
            wv[2] = cvtpk(cp[4 * HS_], cp[5 * HS_]);
            wv[3] = cvtpk(cp[6 * HS_], cp[7 * HS_]);
            ob[nt * 64 + l] = wv;
        }
    }

    {
        const int r = tid >> 3, k0 = (tid & 7) * 16;
        const float* rp = hs + r * HS_ + k0;
        float s1 = 0.f, s2 = 0.f;
#pragma unroll
        for (int k = 0; k < 16; ++k) {
            s1 += rp[k] * wa1[k0 + k];
            s2 += rp[k] * wa2[k0 + k];
        }
        s1 += __shfl_xor(s1, 1, 64); s2 += __shfl_xor(s2, 1, 64);
        s1 += __shfl_xor(s1, 2, 64); s2 += __shfl_xor(s2, 2, 64);
        s1 += __shfl_xor(s1, 4, 64); s2 += __shfl_xor(s2, 4, 64);
        if ((tid & 7) == 0) {
            f1all[b * M_ + t * 32 + r] = s1;
            f2all[b * M_ + t * 32 + r] = s2;
        }
    }
}

// ---------------------------------------------------------------------------
// Phase 2: 1024 blocks x 256 thr. Block = 32 rows; wave (rg = w&1, wh = w>>1)
// = 16 rows x token half (32 tiles). Two tiles in flight per step (one per
// half), 32 steps, one raw barrier per step. Masks in VGPRs via shfl.
// ---------------------------------------------------------------------------
__global__ __launch_bounds__(256, 3) void k_main(
    const u32* __restrict__ mask, const u16* __restrict__ hbf,
    const float* __restrict__ f1all, const float* __restrict__ f2all,
    const float* __restrict__ W, float* __restrict__ out)
{
    __shared__ char  dyn[40960];          // lbuf 32768 | f2s 8192 (Tsum alias)
    __shared__ float dens2[64];

    u32x4* lbuf = (u32x4*)dyn;            // [buf][half][512] u32x4
    float* f2s  = (float*)(dyn + 32768);  // [2048] 8 KB
    float* Tsum = (float*)dyn;            // [32][WT_] 16896 B (epilogue alias)

    const int tid  = threadIdx.x;
    const int w    = tid >> 6;
    const int l    = tid & 63;
    const int lc   = l & 15;
    const int quad = l >> 4;
    const int rg   = w & 1;               // row group (16 rows)
    const int wh   = w >> 1;              // token half (== tid>>7)
    const int ti   = tid & 127;           // staging index within half

    const u32 bid = blockIdx.x;
    const u32 lg  = (bid & 7) * 128 + (bid >> 3);   // XCD x: batches 2x,2x+1
    const int b   = lg >> 6;
    const int i0  = (lg & 63) * 32;
    const int row = i0 + rg * 16 + lc;

    // stage f2all[b] -> LDS (8 KB)
    {
        const int o = tid * 8;
        float4_ v0 = *(const float4_*)(f2all + b * M_ + o);
        float4_ v1 = *(const float4_*)(f2all + b * M_ + o + 4);
        *(float4_*)(f2s + o)     = v0;
        *(float4_*)(f2s + o + 4) = v1;
    }

    // masks -> VGPRs: thread (row, quad) holds words [wh*32 + quad*8 + j]
    const u32* mrow = mask + ((size_t)(b * M_ + row)) * 64 + wh * 32 + quad * 8;
    u32x4 mwa = *(const u32x4*)(mrow);
    u32x4 mwb = *(const u32x4*)(mrow + 4);

    const float f1r = f1all[b * M_ + row];
    const u32x4* hbs = (const u32x4*)hbf + (size_t)b * 32768;
    const int msh = quad * 8;

    // prologue: stage tiles {0, 32} (each half's tile 0) into buf0
    {
        const int Th = wh * 32;
#pragma unroll
        for (int j = 0; j < 4; ++j)
            lbuf[wh * 512 + ti + 128 * j] = hbs[Th * 512 + ti + 128 * j];
    }
    __syncthreads();   // f2s + buf0 ready (prologue-only full drain)

    float denacc = 0.f;
    float4_ acc[8];
#pragma unroll
    for (int nt = 0; nt < 8; ++nt) acc[nt] = (float4_){0.f, 0.f, 0.f, 0.f};

#define SC(GE, GO, BE, BO, IDX)                                 \
        {                                                       \
            float xe = f1r + (GE); xe = fmaxf(xe, ALPHA_ * xe); \
            float xo = f1r + (GO); xo = fmaxf(xo, ALPHA_ * xo); \
            float ee = (mq & (1u << (BE))) ? __expf(xe) : 0.f;  \
            float eo = (mq & (1u << (BO))) ? __expf(xo) : 0.f;  \
            u32 pk = cvtpk(ee, eo);                             \
            d += __uint_as_float(pk << 16);                     \
            d += __uint_as_float(pk & 0xFFFF0000u);             \
            pw[IDX] = pk;                                       \
        }

// Step K (LITERAL 0..31). Tile for this wave: T = wh*32 + K.
//  1. issue stage loads for step K+1 (own half's next tile)
//  2. ds_read current buf; mask via shfl (static reg index, K literal);
//     f2 pair; scores; den; 8 MFMA
//  3. ds_write staged regs to next buf (auto-wait = counted vmcnt, slack =
//     the whole compute phase)
//  4. lgkmcnt(0) + raw s_barrier (no vmcnt drain)
#define STEP(K)                                                               \
    {                                                                         \
        const int kn = ((K) < 31) ? (K) + 1 : 31;                             \
        u32x4 s0 = hbs[(wh * 32 + kn) * 512 + ti];                            \
        u32x4 s1 = hbs[(wh * 32 + kn) * 512 + ti + 128];                      \
        u32x4 s2 = hbs[(wh * 32 + kn) * 512 + ti + 256];                      \
        u32x4 s3 = hbs[(wh * 32 + kn) * 512 + ti + 384];                      \
        __builtin_amdgcn_sched_barrier(0);                                    \
        const u32x4* cb = lbuf + (((K) & 1) * 2 + wh) * 512;                  \
        u32x4 bb[8];                                                          \
        _Pragma("unroll")                                                     \
        for (int nt = 0; nt < 8; ++nt) bb[nt] = cb[nt * 64 + l];              \
        u32 mrw = __shfl((((K) & 7) < 4) ? mwa[(K) & 3] : mwb[(K) & 3],       \
                         (((K) >> 3) << 4) + lc, 64);                         \
        const u32 mq = mrw >> msh;                                            \
        float4_ g0 = *(const float4_*)(f2s + (wh * 32 + (K)) * 32 + quad * 8);\
        float4_ g1 = *(const float4_*)(f2s + (wh * 32 + (K)) * 32 + quad * 8  \
                                       + 4);                                  \
        u32x4 pw;                                                             \
        float d = 0.f;                                                        \
        SC(g0[0], g0[1], 0, 1, 0)                                             \
        SC(g0[2], g0[3], 2, 3, 1)                                             \
        SC(g1[0], g1[1], 4, 5, 2)                                             \
        SC(g1[2], g1[3], 6, 7, 3)                                             \
        denacc += d;                                                          \
        const short8 af = __builtin_bit_cast(short8, pw);                     \
        _Pragma("unroll")                                                     \
        for (int nt = 0; nt < 8; ++nt)                                        \
            acc[nt] = __builtin_amdgcn_mfma_f32_16x16x32_bf16(                \
                af, __builtin_bit_cast(short8, bb[nt]), acc[nt], 0, 0, 0);    \
        __builtin_amdgcn_sched_barrier(0);                                    \
        u32x4* nb = lbuf + ((((K) + 1) & 1) * 2 + wh) * 512;                  \
        nb[ti]       = s0;                                                    \
        nb[ti + 128] = s1;                                                    \
        nb[ti + 256] = s2;                                                    \
        nb[ti + 384] = s3;                                                    \
        asm volatile("s_waitcnt lgkmcnt(0)" ::: "memory");                    \
        __builtin_amdgcn_s_barrier();                                         \
        __builtin_amdgcn_sched_barrier(0);                                    \
    }

#define STEP4(K) STEP(K) STEP((K) + 1) STEP((K) + 2) STEP((K) + 3)
    STEP4(0)  STEP4(4)  STEP4(8)  STEP4(12)
    STEP4(16) STEP4(20) STEP4(24) STEP4(28)
#undef STEP4
#undef STEP
#undef SC

    // mw[K&3] with K literal: mwa holds j=0..3, mwb j=4..7; (K&7)<4 selects.
    // (index (K)&3 == ((K)&7)&3 == j or j-4 as required.)

    // ---- denom: reduce over the 4 quads; slot per (wh, row) ----
    denacc += __shfl_xor(denacc, 16, 64);
    denacc += __shfl_xor(denacc, 32, 64);
    if (quad == 0) dens2[wh * 32 + rg * 16 + lc] = denacc;
    __syncthreads();   // loop LDS dead; Tsum alias safe

    // ---- merge token-half partials: wh0 writes, wh1 adds ----
    if (wh == 0) {
#pragma unroll
        for (int nt = 0; nt < 8; ++nt)
#pragma unroll
            for (int mm = 0; mm < 4; ++mm)
                Tsum[(rg * 16 + quad * 4 + mm) * WT_ + nt * 16 + lc] = acc[nt][mm];
    }
    __syncthreads();
    if (wh == 1) {
#pragma unroll
        for (int nt = 0; nt < 8; ++nt)
#pragma unroll
            for (int mm = 0; mm < 4; ++mm)
                Tsum[(rg * 16 + quad * 4 + mm) * WT_ + nt * 16 + lc] += acc[nt][mm];
    }
    __syncthreads();

    // ---- epilogue: out = elu( (T @ W_fp32) / den ), 32 rows ----
    {
        const int r  = tid >> 3;
        const int n0 = (tid & 7) * 8;
        const float den  = dens2[r] + dens2[32 + r];
        const float rden = (den > 0.f) ? (1.f / den) : 0.f;
        float u[8];
#pragma unroll
        for (int nn = 0; nn < 8; ++nn) u[nn] = 0.f;
#pragma unroll 4
        for (int k = 0; k < FIN_; ++k) {
            const float tv = Tsum[r * WT_ + k];
            float4_ wv0 = *(const float4_*)(W + k * F_ + n0);
            float4_ wv1 = *(const float4_*)(W + k * F_ + n0 + 4);
            u[0] += tv * wv0[0]; u[1] += tv * wv0[1];
            u[2] += tv * wv0[2]; u[3] += tv * wv0[3];
            u[4] += tv * wv1[0]; u[5] += tv * wv1[1];
            u[6] += tv * wv1[2]; u[7] += tv * wv1[3];
        }
        float4_ o0, o1;
#pragma unroll
        for (int nn = 0; nn < 8; ++nn) {
            float hp = u[nn] * rden;
            float o  = hp > 0.f ? hp : expm1f(hp);
            if (nn < 4) o0[nn] = o; else o1[nn - 4] = o;
        }
        float* op = out + ((size_t)(b * M_ + i0 + r)) * F_ + n0;
        *(float4_*)op       = o0;
        *(float4_*)(op + 4) = o1;
    }
}

// ---------------------------------------------------------------------------
extern "C" void kernel_launch(void* const* d_in, const int* in_sizes, int n_in,
                              void* d_out, int out_size, void* d_ws, size_t ws_size,
                              hipStream_t stream)
{
    (void)out_size; (void)ws_size;
    const float* h  = (const float*)d_in[0];
    const int* adjp = (const int*)d_in[1];
    const float* Wp = (const float*)d_in[2];
    const float* ap = (const float*)d_in[3];
    for (int i = 0; i < n_in; ++i) {
        long s = in_sizes[i];
        if      (s == 4194304L)  h    = (const float*)d_in[i];
        else if (s == 67108864L) adjp = (const int*)d_in[i];
        else if (s == 8192L)     Wp   = (const float*)d_in[i];
        else if (s == 128L)      ap   = (const float*)d_in[i];
    }
    u16*   hbf   = (u16*)d_ws;                                  // 8 MB
    float* f1all = (float*)((char*)d_ws + (8u << 20));          // 128 KB
    float* f2all = f1all + 16 * M_;                             // 128 KB
    u32*   maskp = (u32*)((char*)d_ws + (16u << 20));           // 8 MB
    k_pp<<<3072, 256, 0, stream>>>(h, adjp, Wp, ap, hbf, f1all, f2all, maskp);
    k_main<<<1024, 256, 0, stream>>>(maskp, hbf, f1all, f2all, Wp, (float*)d_out);
}